// Round 5
// baseline (192.390 us; speedup 1.0000x reference)
//
#include <hip/hip_runtime.h>

// out0 = cumsum(z, axis=0), z fp32 [8192, 64, 128] -> 8192 rows x 8192 contiguous cols.
// out1 = previous_loss (1 float) at d_out[8192*8192].
//
// 3-pass chunked scan, run as 2 COLUMN PANELS of 134 MB so that k_apply's
// re-read of z hits the 256 MiB Infinity Cache: reuse distance between
// k_partial's read of a line and k_apply's re-read is ~150 MB (panel tail +
// scan + writes-so-far), safely under MALL capacity. Full-width (round 3) the
// distance is ~280 MB -> misses; that kernel measured at the HBM structural
// limit (136.5 us). nt stores on the output stream limit write pollution.

typedef float f4 __attribute__((ext_vector_type(4)));

constexpr int NROWS  = 8192;
constexpr int NCOLS  = 8192;
constexpr int NCOL4  = NCOLS / 4;      // 2048 float4 per row
constexpr int TPB    = 256;
constexpr int KCH    = 128;            // row chunks
constexpr int RR     = NROWS / KCH;    // 64 rows per chunk

constexpr int NPAN   = 2;
constexpr int PANW4  = NCOL4 / NPAN;   // 1024 float4 cols per panel
constexpr int PT     = PANW4 / TPB;    // 4 tiles per panel
constexpr int PGRID  = KCH * PT;       // 512 blocks per panel kernel

// Pass 1 (per panel): per-column sums of each row-chunk -> part[KCH][NCOLS]
__global__ __launch_bounds__(TPB) void k_partial(const f4* __restrict__ z,
                                                 f4* __restrict__ part,
                                                 int colBase4) {
    const int tile  = blockIdx.x & (PT - 1);
    const int chunk = blockIdx.x / PT;
    const int c4    = colBase4 + tile * TPB + threadIdx.x;
    const f4* p = z + (size_t)chunk * RR * NCOL4 + c4;
    f4 a = (f4)0.f;
    #pragma unroll 16
    for (int r = 0; r < RR; ++r) a += p[(size_t)r * NCOL4];
    part[(size_t)chunk * NCOL4 + c4] = a;
}

// Pass 2 (per panel): in-place serial EXCLUSIVE scan over the KCH chunk sums.
__global__ __launch_bounds__(TPB) void k_scan(float* __restrict__ part,
                                              int colBaseF,
                                              const float* __restrict__ prev,
                                              float* __restrict__ out_tail) {
    const int c = colBaseF + blockIdx.x * TPB + threadIdx.x;
    float run = 0.f;
    #pragma unroll 16
    for (int k = 0; k < KCH; ++k) {
        const size_t i = (size_t)k * NCOLS + c;
        float v = part[i];
        part[i] = run;
        run += v;
    }
    if (colBaseF == 0 && blockIdx.x == 0 && threadIdx.x == 0)
        out_tail[0] = prev[0];
}

// Pass 3 (per panel): re-read z (Infinity-Cache-resident), add exclusive chunk
// prefix, write inclusive cumsum with nontemporal stores.
__global__ __launch_bounds__(TPB) void k_apply(const f4* __restrict__ z,
                                               const f4* __restrict__ part,
                                               f4* __restrict__ out,
                                               int colBase4) {
    const int tile  = blockIdx.x & (PT - 1);
    const int chunk = blockIdx.x / PT;
    const int c4    = colBase4 + tile * TPB + threadIdx.x;
    f4 a = part[(size_t)chunk * NCOL4 + c4];
    const f4* p = z   + (size_t)chunk * RR * NCOL4 + c4;
    f4*       q = out + (size_t)chunk * RR * NCOL4 + c4;
    #pragma unroll 8
    for (int r = 0; r < RR; ++r) {
        a += p[(size_t)r * NCOL4];
        __builtin_nontemporal_store(a, &q[(size_t)r * NCOL4]);
    }
}

extern "C" void kernel_launch(void* const* d_in, const int* in_sizes, int n_in,
                              void* d_out, int out_size, void* d_ws, size_t ws_size,
                              hipStream_t stream) {
    const f4*    z    = (const f4*)d_in[0];
    const float* prev = (const float*)d_in[1];
    float*       out  = (float*)d_out;
    float*       part = (float*)d_ws;    // KCH*NCOLS floats = 4 MiB
    float*       tail = out + (size_t)NROWS * NCOLS;

    for (int pan = 0; pan < NPAN; ++pan) {
        const int colBase4 = pan * PANW4;
        const int colBaseF = colBase4 * 4;
        k_partial<<<PGRID, TPB, 0, stream>>>(z, (f4*)part, colBase4);
        k_scan<<<(PANW4 * 4) / TPB, TPB, 0, stream>>>(part, colBaseF, prev, tail);
        k_apply<<<PGRID, TPB, 0, stream>>>(z, (const f4*)part, (f4*)out, colBase4);
    }
}

// Round 6
// 187.814 us; speedup vs baseline: 1.0244x; 1.0244x over previous
//
#include <hip/hip_runtime.h>

// out0 = cumsum(z, axis=0), z fp32 [8192, 64, 128] -> 8192 rows x 8192 contiguous cols.
// out1 = previous_loss (1 float) at d_out[8192*8192].
//
// Write-retention 3-pass: instead of re-reading z (round 3: read stream never
// survives MALL next to a write stream), k_local writes the LOCAL cumsum to out
// (normal stores -> dirty-resident in 256 MiB Infinity Cache; z loads marked
// nontemporal so they don't compete), and k_addpfx does an IN-PLACE
// out += prefix[chunk] -- allocating nothing new, so the resident lines are
// read back as MALL hits and written to HBM exactly once on final eviction.
// Summation order identical to the round-3 kernel (absmax 1.0).

typedef float f4 __attribute__((ext_vector_type(4)));

constexpr int NROWS = 8192;
constexpr int NCOLS = 8192;
constexpr int NCOL4 = NCOLS / 4;     // 2048 float4 per row
constexpr int TPB   = 256;
constexpr int KCH   = 128;           // row chunks
constexpr int RR    = NROWS / KCH;   // 64 rows per chunk
constexpr int CT    = NCOL4 / TPB;   // 8 column tiles -> 1024 blocks

// Pass 1: per-chunk local running cumsum -> out (resident), aggregate -> part.
__global__ __launch_bounds__(TPB) void k_local(const f4* __restrict__ z,
                                               f4* __restrict__ out,
                                               f4* __restrict__ part) {
    const int tile  = blockIdx.x & (CT - 1);
    const int chunk = blockIdx.x >> 3;
    const int c4    = tile * TPB + threadIdx.x;
    const f4* p = z   + (size_t)chunk * RR * NCOL4 + c4;
    f4*       q = out + (size_t)chunk * RR * NCOL4 + c4;
    f4 a = (f4)0.f;
    #pragma unroll 8
    for (int r = 0; r < RR; ++r) {
        a += __builtin_nontemporal_load(&p[(size_t)r * NCOL4]);
        q[(size_t)r * NCOL4] = a;                 // normal store: keep in MALL
    }
    part[(size_t)chunk * NCOL4 + c4] = a;
}

// Pass 2: in-place serial EXCLUSIVE scan over the KCH chunk sums, per column.
__global__ __launch_bounds__(TPB) void k_scan(float* __restrict__ part,
                                              const float* __restrict__ prev,
                                              float* __restrict__ out_tail) {
    const int c = blockIdx.x * TPB + threadIdx.x; // 0..8191
    float run = 0.f;
    #pragma unroll 16
    for (int k = 0; k < KCH; ++k) {
        const size_t i = (size_t)k * NCOLS + c;
        float v = part[i];
        part[i] = run;
        run += v;
    }
    if (blockIdx.x == 0 && threadIdx.x == 0) out_tail[0] = prev[0];
}

// Pass 3: in-place out += exclusive chunk prefix (chunk 0 adds 0.0).
// Reverse chunk order = most-recently-written (still-resident) lines first.
__global__ __launch_bounds__(TPB) void k_addpfx(f4* __restrict__ out,
                                                const f4* __restrict__ part) {
    const int tile  = blockIdx.x & (CT - 1);
    const int chunk = KCH - 1 - (blockIdx.x >> 3);
    const int c4    = tile * TPB + threadIdx.x;
    const f4 pre = part[(size_t)chunk * NCOL4 + c4];
    f4* q = out + (size_t)chunk * RR * NCOL4 + c4;
    #pragma unroll 8
    for (int r = 0; r < RR; ++r)
        q[(size_t)r * NCOL4] += pre;
}

extern "C" void kernel_launch(void* const* d_in, const int* in_sizes, int n_in,
                              void* d_out, int out_size, void* d_ws, size_t ws_size,
                              hipStream_t stream) {
    const f4*    z    = (const f4*)d_in[0];
    const float* prev = (const float*)d_in[1];
    float*       out  = (float*)d_out;
    float*       part = (float*)d_ws;   // KCH*NCOLS floats = 4 MiB
    float*       tail = out + (size_t)NROWS * NCOLS;

    k_local<<<KCH * CT, TPB, 0, stream>>>(z, (f4*)out, (f4*)part);
    k_scan<<<NCOLS / TPB, TPB, 0, stream>>>(part, prev, tail);
    k_addpfx<<<KCH * CT, TPB, 0, stream>>>((f4*)out, (const f4*)part);
}